// Round 15
// baseline (1010.025 us; speedup 1.0000x reference)
//
#include <hip/hip_runtime.h>
#include <hip/hip_bf16.h>

#define NN 50000      // nodes
#define NE 800000     // edges
#define DD 128        // hidden dim
#define NB 5          // GIN blocks
#define NG 512        // graphs
#define NC 10         // classes
#define BN_EPS 1e-5f
#define EPS1 129.0f   // 1 + eps_gin
#define GATHER_BLOCKS 12500   // NN/4
#define GP_BLOCKS 512         // gemm_pair grid (>=391 tiles, all co-resident 2/CU)
#define GEMM_TILES 391        // ceil(NN/128)

typedef __hip_bfloat16 bf16;
typedef __attribute__((ext_vector_type(8))) short short8;
typedef __attribute__((ext_vector_type(4))) float f32x4;

__device__ __forceinline__ float b2f(const bf16 v) { return __bfloat162float(v); }
__device__ __forceinline__ float us2f(unsigned int s) {
    return __uint_as_float((s & 0xffffu) << 16);
}
__device__ __forceinline__ unsigned pack2(float a, float b) {
    union { bf16 h; unsigned short u; } ua, ub;
    ua.h = __float2bfloat16(a); ub.h = __float2bfloat16(b);
    return ((unsigned)ub.u << 16) | (unsigned)ua.u;
}
__device__ __forceinline__ short f2bfs(float f) {
    union { bf16 h; short s; } u; u.h = __float2bfloat16(f); return u.s;
}

// device-scope grid barrier (all blocks co-resident by construction)
__device__ __forceinline__ void gbar(int* cnt, int* gen, int nb) {
    __syncthreads();
    if (threadIdx.x == 0) {
        __threadfence();
        int g = atomicAdd(gen, 0);
        if (atomicAdd(cnt, 1) == nb - 1) {
            atomicExch(cnt, 0);
            atomicAdd(gen, 1);
        } else {
            while (atomicAdd(gen, 0) == g) __builtin_amdgcn_s_sleep(2);
        }
        __threadfence();
    }
    __syncthreads();
}

// ---- workspace layout (float offsets) ----
#define OFF_AGGH   0            // bf16 [NN,128]
#define OFF_XF     3200000      // bf16 [NN,128]
#define OFF_H1     6400000      // bf16 [NN,128]
#define OFF_FEATS  9600000      // fp32 512*640
#define OFF_CSA    9927680      // 256
#define OFF_CSB    9927936      // 256
#define OFF_SC6    9928192      // 640
#define OFF_SH6    9928832      // 640
#define OFF_FLAGS  9929472      // 8 ints
#define OFF_PARAMS 9929480      // bf16 region
#define OFF_DEG    10055680     // int 50000
#define OFF_OFFS   10105680     // int 50001
#define OFF_ELIST  10155712     // int 800000
#define OFF_BDEG   10955712     // int 512
#define OFF_BOFFS  10956224     // int 513
#define OFF_RANK   10956800     // int 50000
#define OFF_PART   11006800     // int 64
#define OFF_BAR    11006864     // int 4: cnt0,gen0,cnt1,gen1

// bf16 param region
#define P_W1T  0
#define P_W2T  81920
#define P_WC1  163840
#define P_B1   245760
#define P_G1   246400
#define P_BE1  247040
#define P_B2   247680
#define P_G2   248320
#define P_BE2  248960
#define P_BNG  249600
#define P_BNB  250240
#define P_BC1  250880
#define P_WC2  251008
#define P_BC2  252288

struct SmallSrc { const void* s[11]; };

// ---- dtype detection (also zeroes bdeg) ----
__global__ void k_detect(const unsigned* __restrict__ xw, const int* __restrict__ eiw,
                         const int* __restrict__ bw, int* flags, int* __restrict__ bdeg) {
    __shared__ int sh[3];
    const int t = threadIdx.x;  // 256
    bdeg[t] = 0; bdeg[256 + t] = 0;
    if (t < 3) sh[t] = 0;
    __syncthreads();
    int c = 0;
    for (int i = 0; i < 16; i++) {
        unsigned w = xw[t * 16 + i];
        unsigned e = (w >> 7) & 0xff;
        c += (e >= 110 && e <= 131) ? 1 : 0;
    }
    atomicAdd(&sh[0], c);
    atomicAdd(&sh[1], (eiw[2 * t + 1] != 0) ? 1 : 0);
    atomicAdd(&sh[2], (bw[2 * t + 1] != 0) ? 1 : 0);
    __syncthreads();
    if (t == 0) {
        flags[0] = (sh[0] > 2048) ? 1 : 0;
        flags[1] = (sh[1] < 8) ? 1 : 0;
        flags[2] = (sh[2] < 8) ? 1 : 0;
    }
}

// ---- batch CSR; also zeroes deg ----
__global__ void k_bhist(const int* __restrict__ flags, const int* __restrict__ batch,
                        int* __restrict__ bdeg, int* __restrict__ deg) {
    int n = blockIdx.x * 256 + threadIdx.x;
    if (n >= NN) return;
    deg[n] = 0;
    int g = flags[2] ? batch[2 * n] : batch[n];
    atomicAdd(&bdeg[g], 1);
}

__launch_bounds__(512)
__global__ void k_bscan(int* __restrict__ bdeg, int* __restrict__ boffs,
                        int* __restrict__ barst) {
    __shared__ int part[512];
    const int t = threadIdx.x;
    if (t < 4) barst[t] = 0;
    int d0 = bdeg[t];
    part[t] = d0;
    __syncthreads();
    for (int d = 1; d < 512; d <<= 1) {
        int v = (t >= d) ? part[t - d] : 0;
        __syncthreads();
        part[t] += v;
        __syncthreads();
    }
    int ex = part[t] - d0;
    boffs[t] = ex;
    bdeg[t] = ex;   // cursor
    if (t == 511) boffs[512] = part[511];
}

__global__ void k_bplace(const int* __restrict__ flags, const int* __restrict__ batch,
                         int* __restrict__ bcur, int* __restrict__ rank) {
    int n = blockIdx.x * 256 + threadIdx.x;
    if (n >= NN) return;
    int g = flags[2] ? batch[2 * n] : batch[n];
    rank[n] = atomicAdd(&bcur[g], 1);
}

// fused: blocks [0,3125): x -> bf16 xfh permuted; blocks [3125,6250): edge hist
__global__ void k_convert_hist(const int* __restrict__ flags, const void* __restrict__ xr,
                               const int* __restrict__ rank, bf16* __restrict__ xfh,
                               const int* __restrict__ ei, int* __restrict__ deg) {
    if (blockIdx.x >= 3125) {
        int e = (blockIdx.x - 3125) * 256 + threadIdx.x;   // NE
        int d = flags[1] ? ei[2 * NE + 2 * e] : ei[NE + e];
        atomicAdd(&deg[rank[d]], 1);
        return;
    }
    int i = blockIdx.x * 256 + threadIdx.x;
    int r = i >> 4, seg = i & 15;
    uint4 o;
    if (flags[0]) {
        o = ((const uint4*)xr)[i];
    } else {
        float4 a = ((const float4*)xr)[2 * i], b = ((const float4*)xr)[2 * i + 1];
        o.x = pack2(a.x, a.y); o.y = pack2(a.z, a.w);
        o.z = pack2(b.x, b.y); o.w = pack2(b.z, b.w);
    }
    ((uint4*)xfh)[(long)rank[r] * 16 + seg] = o;
}

// unified param convert
__global__ void k_convert_params(const int* __restrict__ flags, const void* w1,
                                 const void* w2, const void* wc1, SmallSrc srcs,
                                 bf16* __restrict__ pb) {
    int i = blockIdx.x * 256 + threadIdx.x;
    if (i < 245760) {
        int which = i / 81920, j = i % 81920;
        const void* src = (which == 0) ? w1 : (which == 1) ? w2 : wc1;
        float v = flags[0] ? us2f(((const unsigned short*)src)[j]) : ((const float*)src)[j];
        if (which == 2) {
            pb[P_WC1 + j] = __float2bfloat16(v);
        } else {
            int layer = j >> 14, rem = j & 16383;
            int k = rem >> 7, c = rem & 127;
            bf16* dst = pb + (which == 0 ? P_W1T : P_W2T);
            dst[(layer << 14) + c * DD + k] = __float2bfloat16(v);
        }
    } else {
        int j = i - 245760;
        if (j >= 6538) return;
        int seg, off;
        if (j < 5120)      { seg = j / 640; off = j - seg * 640; }
        else if (j < 5248) { seg = 8;  off = j - 5120; }
        else if (j < 6528) { seg = 9;  off = j - 5248; }
        else               { seg = 10; off = j - 6528; }
        const void* s = srcs.s[seg];
        float v = flags[0] ? us2f(((const unsigned short*)s)[off]) : ((const float*)s)[off];
        pb[P_B1 + j] = __float2bfloat16(v);
    }
}

__global__ void k_scan_part(const int* __restrict__ deg, int* __restrict__ part) {
    __shared__ int red[256];
    const int b = blockIdx.x, t = threadIdx.x;   // 49 x 256
    int i0 = b * 1024 + t * 4;
    int s = 0;
    if (i0 + 3 < NN) {
        int4 v = *(const int4*)(deg + i0);
        s = v.x + v.y + v.z + v.w;
    } else {
        for (int k = 0; k < 4; k++) if (i0 + k < NN) s += deg[i0 + k];
    }
    red[t] = s;
    __syncthreads();
    for (int d = 128; d > 0; d >>= 1) {
        if (t < d) red[t] += red[t + d];
        __syncthreads();
    }
    if (t == 0) part[b] = red[0];
}

__global__ void k_scan_apply(int* __restrict__ deg, const int* __restrict__ part,
                             int* __restrict__ offs) {
    __shared__ int red[256];
    __shared__ int base_sh, total_sh;
    const int b = blockIdx.x, t = threadIdx.x;   // 49 x 256
    if (t < 64) {
        int v = (t < 49) ? part[t] : 0;
        int s = v;
        for (int d = 1; d < 64; d <<= 1) {
            int x = __shfl_up(s, d);
            if (t >= d) s += x;
        }
        if (t == b)  base_sh = s - v;
        if (t == 48) total_sh = s;
    }
    int i0 = b * 1024 + t * 4;
    int v[4]; int s = 0;
    #pragma unroll
    for (int k = 0; k < 4; k++) {
        int idx = i0 + k;
        v[k] = (idx < NN) ? deg[idx] : 0;
        s += v[k];
    }
    red[t] = s;
    __syncthreads();
    for (int d = 1; d < 256; d <<= 1) {
        int x = (t >= d) ? red[t - d] : 0;
        __syncthreads();
        red[t] += x;
        __syncthreads();
    }
    if (b == 0 && t == 0) offs[NN] = total_sh;
    int pre = base_sh + ((t == 0) ? 0 : red[t - 1]);
    #pragma unroll
    for (int k = 0; k < 4; k++) {
        int idx = i0 + k;
        if (idx < NN) { offs[idx] = pre; deg[idx] = pre; pre += v[k]; }
    }
}

__global__ void k_place(const int* __restrict__ flags, const int* __restrict__ ei,
                        const int* __restrict__ rank, int* __restrict__ curs,
                        int* __restrict__ elist) {
    int e = blockIdx.x * 256 + threadIdx.x;   // NE
    int s, d;
    if (flags[1]) { s = ei[2 * e]; d = ei[2 * NE + 2 * e]; }
    else          { s = ei[e];     d = ei[NE + e]; }
    elist[atomicAdd(&curs[rank[d]], 1)] = rank[s];
}

// pool body (256 threads): per-graph sum of bn(xfh rows) -> feats_blk[g*640..]
__device__ __forceinline__ void pool_body(int g, int t, const bf16* __restrict__ xfh,
                                          const int* __restrict__ boffs,
                                          const float* __restrict__ csB,
                                          const bf16* __restrict__ g2,
                                          const bf16* __restrict__ be2,
                                          float* __restrict__ feats_blk) {
    __shared__ float2 red[3][64];
    const int l = t & 63;
    const int h = t >> 6;
    const int lo = boffs[g], hi = boffs[g + 1];
    const unsigned* xw = (const unsigned*)xfh;
    float s0 = 0.f, s1 = 0.f;
    for (int n = lo + h; n < hi; n += 4) {
        unsigned p = xw[(long)n * 64 + l];
        s0 += us2f(p); s1 += us2f(p >> 16);
    }
    if (h) red[h - 1][l] = make_float2(s0, s1);
    __syncthreads();
    if (h == 0) {
        s0 += red[0][l].x + red[1][l].x + red[2][l].x;
        s1 += red[0][l].y + red[1][l].y + red[2][l].y;
        int c = l * 2;
        float mu0 = csB[c] * (1.f / NN);
        float var0 = csB[128 + c] * (1.f / NN) - mu0 * mu0;
        float sc0 = b2f(g2[c]) * rsqrtf(var0 + BN_EPS);
        float sh0 = b2f(be2[c]) - mu0 * sc0;
        float mu1 = csB[c + 1] * (1.f / NN);
        float var1 = csB[128 + c + 1] * (1.f / NN) - mu1 * mu1;
        float sc1 = b2f(g2[c + 1]) * rsqrtf(var1 + BN_EPS);
        float sh1 = b2f(be2[c + 1]) - mu1 * sc1;
        float cnt = (float)(hi - lo);
        float* fp = feats_blk + (long)g * (NB * DD) + c;
        fp[0] = sc0 * s0 + cnt * sh0;
        fp[1] = sc1 * s1 + cnt * sh1;
    }
    __syncthreads();
}

// combined: blocks [0,12500) gather layer i; [12500,13012) pool layer i-1.
__global__ void k_gather_pool(const int* __restrict__ offs, const int* __restrict__ elist,
                              const bf16* __restrict__ xfh, bf16* __restrict__ aggh,
                              const float* __restrict__ csB, const bf16* __restrict__ g2,
                              const bf16* __restrict__ be2, float* __restrict__ csA_zero,
                              const int* __restrict__ boffs, float* __restrict__ feats_prev) {
    if (blockIdx.x >= GATHER_BLOCKS) {
        if (feats_prev)
            pool_body(blockIdx.x - GATHER_BLOCKS, threadIdx.x, xfh, boffs,
                      csB, g2, be2, feats_prev);
        return;
    }
    if (blockIdx.x == 0) csA_zero[threadIdx.x] = 0.f;   // 256 floats
    const int w = threadIdx.x >> 6;
    const int lane = threadIdx.x & 63;
    const int n = blockIdx.x * 4 + w;
    const int base = offs[n], end = offs[n + 1];
    const unsigned* xw = (const unsigned*)xfh;
    unsigned sp = xw[(long)n * 64 + lane];
    float ax = EPS1 * us2f(sp), ay = EPS1 * us2f(sp >> 16);
    for (int i = base; i < end; i += 64) {
        int cnt = min(64, end - i);
        int e = (i + lane < end) ? elist[i + lane] : 0;
        int j = 0;
        for (; j + 16 <= cnt; j += 16) {
            unsigned p[16];
            #pragma unroll
            for (int q = 0; q < 16; q++) {
                int sj = __shfl(e, j + q);
                p[q] = xw[(long)sj * 64 + lane];
            }
            #pragma unroll
            for (int q = 0; q < 16; q++) {
                ax += us2f(p[q]); ay += us2f(p[q] >> 16);
            }
        }
        for (; j + 8 <= cnt; j += 8) {
            unsigned p[8];
            #pragma unroll
            for (int q = 0; q < 8; q++) {
                int sj = __shfl(e, j + q);
                p[q] = xw[(long)sj * 64 + lane];
            }
            #pragma unroll
            for (int q = 0; q < 8; q++) {
                ax += us2f(p[q]); ay += us2f(p[q] >> 16);
            }
        }
        for (; j < cnt; j++) {
            int sj = __shfl(e, j);
            unsigned p = xw[(long)sj * 64 + lane];
            ax += us2f(p); ay += us2f(p >> 16);
        }
    }
    if (csB) {
        int c = lane * 2;
        float fac = (float)(end - base) + EPS1;
        float mu0 = csB[c] * (1.f / NN);
        float var0 = csB[128 + c] * (1.f / NN) - mu0 * mu0;
        float sc0 = b2f(g2[c]) * rsqrtf(var0 + BN_EPS);
        float sh0 = b2f(be2[c]) - mu0 * sc0;
        float mu1 = csB[c + 1] * (1.f / NN);
        float var1 = csB[128 + c + 1] * (1.f / NN) - mu1 * mu1;
        float sc1 = b2f(g2[c + 1]) * rsqrtf(var1 + BN_EPS);
        float sh1 = b2f(be2[c + 1]) - mu1 * sc1;
        ax = sc0 * ax + fac * sh0;
        ay = sc1 * ay + fac * sh1;
    }
    ((unsigned*)aggh)[(long)n * 64 + lane] = pack2(ax, ay);
}

// ---- GEMM tile body (512 threads, 128 rows), A-direct + LDS W + epilogue v2 ----
#define WS_S 136
__device__ __forceinline__ void gemm_tile(const bf16* __restrict__ A,
                                          const bf16* __restrict__ WT,
                                          const bf16* __restrict__ bias,
                                          const float* __restrict__ s_sc,
                                          const float* __restrict__ s_sh, bool do_bn,
                                          bf16* __restrict__ Out,
                                          float* __restrict__ cs_out,
                                          short* Ws, float* s_cs, int tile, int t) {
    const int row0 = tile * 128;
    if (t < 256) s_cs[t] = 0.f;
    {   // stage WT (2048 uint4)
        const uint4* Wg = (const uint4*)WT;
        #pragma unroll
        for (int i = 0; i < 4; i++) {
            int idx = i * 512 + t;
            int row = idx >> 4, seg = idx & 15;
            *(uint4*)(&Ws[row * WS_S + seg * 8]) = Wg[idx];
        }
    }
    __syncthreads();

    const int w = t >> 6;
    const int lane = t & 63;
    const int m = lane & 15;
    const int half = lane >> 4;
    const int r = row0 + w * 16 + m;

    short8 afrag[4];
    if (r < NN) {
        #pragma unroll
        for (int kk = 0; kk < 4; kk++)
            afrag[kk] = *(const short8*)(A + (long)r * DD + kk * 32 + half * 8);
        if (do_bn) {
            #pragma unroll
            for (int kk = 0; kk < 4; kk++) {
                int c0 = kk * 32 + half * 8;
                uint4 p = *(uint4*)&afrag[kk];
                float v0 = us2f(p.x) * s_sc[c0+0] + s_sh[c0+0];
                float v1 = us2f(p.x >> 16) * s_sc[c0+1] + s_sh[c0+1];
                float v2 = us2f(p.y) * s_sc[c0+2] + s_sh[c0+2];
                float v3 = us2f(p.y >> 16) * s_sc[c0+3] + s_sh[c0+3];
                float v4 = us2f(p.z) * s_sc[c0+4] + s_sh[c0+4];
                float v5 = us2f(p.z >> 16) * s_sc[c0+5] + s_sh[c0+5];
                float v6 = us2f(p.w) * s_sc[c0+6] + s_sh[c0+6];
                float v7 = us2f(p.w >> 16) * s_sc[c0+7] + s_sh[c0+7];
                p.x = pack2(v0, v1); p.y = pack2(v2, v3);
                p.z = pack2(v4, v5); p.w = pack2(v6, v7);
                afrag[kk] = *(short8*)&p;
            }
        }
    } else {
        #pragma unroll
        for (int kk = 0; kk < 4; kk++) afrag[kk] = (short8){0,0,0,0,0,0,0,0};
    }

    f32x4 acc[8];
    #pragma unroll
    for (int nt = 0; nt < 8; nt++) acc[nt] = (f32x4){0.f, 0.f, 0.f, 0.f};

    #pragma unroll
    for (int nt = 0; nt < 8; nt++) {
        const short* wrow = &Ws[(nt * 16 + m) * WS_S + half * 8];
        #pragma unroll
        for (int kk = 0; kk < 4; kk++) {
            short8 b = *(const short8*)(wrow + kk * 32);
            acc[nt] = __builtin_amdgcn_mfma_f32_16x16x32_bf16(afrag[kk], b, acc[nt], 0, 0, 0);
        }
    }

    __syncthreads();               // done reading Ws -> reuse as Cs
    short* Cs = Ws;
    #pragma unroll
    for (int nt = 0; nt < 8; nt++) {
        int col = nt * 16 + m;
        float bi = b2f(bias[col]);
        float ps = 0.f, pq = 0.f;
        #pragma unroll
        for (int reg = 0; reg < 4; reg++) {
            int rr = row0 + w * 16 + half * 4 + reg;
            float o = fmaxf(acc[nt][reg] + bi, 0.f);
            Cs[(w * 16 + half * 4 + reg) * WS_S + col] = f2bfs(o);
            if (rr < NN) { ps += o; pq += o * o; }
        }
        ps += __shfl_xor(ps, 16); ps += __shfl_xor(ps, 32);
        pq += __shfl_xor(pq, 16); pq += __shfl_xor(pq, 32);
        if (half == 0) {
            atomicAdd(&s_cs[col], ps);
            atomicAdd(&s_cs[128 + col], pq);
        }
    }
    __syncthreads();
    #pragma unroll
    for (int i = 0; i < 4; i++) {
        int idx = i * 512 + t;
        int row = idx >> 4, seg = idx & 15;
        int rr = row0 + row;
        if (rr < NN)
            *(uint4*)(Out + (long)rr * DD + seg * 8) = *(uint4*)(&Cs[row * WS_S + seg * 8]);
    }
    if (t < 256) atomicAdd(&cs_out[t], s_cs[t]);
    __syncthreads();
}

// fused GEMM1 -> grid barrier -> GEMM2 (one launch per layer)
__launch_bounds__(512)
__global__ void k_gemm_pair(const bf16* __restrict__ aggh, bf16* __restrict__ h1h,
                            bf16* __restrict__ xfh,
                            const bf16* __restrict__ W1T, const bf16* __restrict__ b1,
                            const bf16* __restrict__ W2T, const bf16* __restrict__ b2,
                            const bf16* __restrict__ g1, const bf16* __restrict__ be1,
                            float* __restrict__ csA, float* __restrict__ csB,
                            int* __restrict__ barst) {
    __shared__ short Ws[128 * WS_S];
    __shared__ float s_cs[256];
    __shared__ float s_sc[DD], s_sh[DD];
    const int t = threadIdx.x;
    const int bid = blockIdx.x;

    // phase 1: GEMM1 aggh->h1h, stats->csA. Idle block 400 zeroes csB.
    if (bid == 400 && t < 256) csB[t] = 0.f;
    if (bid < GEMM_TILES)
        gemm_tile(aggh, W1T, b1, nullptr, nullptr, false, h1h, csA, Ws, s_cs, bid, t);

    gbar(&barst[0], &barst[1], GP_BLOCKS);

    // phase 2: bn1 coeffs from csA, then GEMM2 h1h->xfh, stats->csB
    if (t < DD) {
        float mu = csA[t] * (1.f / NN);
        float var = csA[128 + t] * (1.f / NN) - mu * mu;
        float sc = b2f(g1[t]) * rsqrtf(var + BN_EPS);
        s_sc[t] = sc;
        s_sh[t] = b2f(be1[t]) - mu * sc;
    }
    __syncthreads();
    if (bid < GEMM_TILES)
        gemm_tile(h1h, W2T, b2, s_sc, s_sh, true, xfh, csB, Ws, s_cs, bid, t);
}

// tail: pool(last layer) -> bar -> feat_stats -> bar -> head. 512 blocks x 256 thr.
__launch_bounds__(256)
__global__ void k_tail(const int* __restrict__ flags, const bf16* __restrict__ xfh,
                       const int* __restrict__ boffs, const float* __restrict__ csB,
                       const bf16* __restrict__ g2, const bf16* __restrict__ be2,
                       float* __restrict__ feats, const bf16* __restrict__ bn_g,
                       const bf16* __restrict__ bn_b, float* __restrict__ sc6,
                       float* __restrict__ sh6,
                       const bf16* __restrict__ Wc1, const bf16* __restrict__ bc1,
                       const bf16* __restrict__ Wc2, const bf16* __restrict__ bc2,
                       void* out, int* __restrict__ barst) {
    const int t = threadIdx.x, bid = blockIdx.x;

    // phase 1: pool last layer (1 graph per block)
    pool_body(bid, t, xfh, boffs, csB, g2, be2, feats + (NB - 1) * DD);

    gbar(&barst[2], &barst[3], GP_BLOCKS);

    // phase 2: feat stats (640 cols over first 3 blocks)
    {
        int j = bid * 256 + t;
        if (j < NB * DD) {
            float s = 0.f, sq = 0.f;
            for (int g = 0; g < NG; g++) {
                float v = feats[(long)g * (NB * DD) + j];
                s += v; sq += v * v;
            }
            float mu = s / NG;
            float var = sq / NG - mu * mu;
            float sc = b2f(bn_g[j]) * rsqrtf(var + BN_EPS);
            sc6[j] = sc;
            sh6[j] = b2f(bn_b[j]) - mu * sc;
        }
    }

    gbar(&barst[2], &barst[3], GP_BLOCKS);

    // phase 3: head (1 graph per block)
    __shared__ float fs[NB * DD];
    __shared__ float f1[DD];
    __shared__ float lg[NC + 2];
    const int g = bid;
    for (int j = t; j < NB * DD; j += 256)
        fs[j] = feats[(long)g * (NB * DD) + j] * sc6[j] + sh6[j];
    __syncthreads();
    if (t < DD) {
        float acc = b2f(bc1[t]);
        for (int j = 0; j < NB * DD; j++) acc += fs[j] * b2f(Wc1[j * DD + t]);
        f1[t] = fmaxf(acc, 0.f);
    }
    __syncthreads();
    if (t < NC) {
        float a = b2f(bc2[t]);
        for (int k = 0; k < DD; k++) a += f1[k] * b2f(Wc2[k * NC + t]);
        lg[t] = a;
    }
    __syncthreads();
    if (t == 0) {
        float m = -1e30f;
        for (int c = 0; c < NC; c++) m = fmaxf(m, lg[c]);
        float s = 0.f;
        for (int c = 0; c < NC; c++) s += expf(lg[c] - m);
        lg[NC] = m + logf(s);
    }
    __syncthreads();
    if (t < NC) {
        float val = lg[t] - lg[NC];
        if (flags[0]) ((bf16*)out)[g * NC + t] = __float2bfloat16(val);
        else          ((float*)out)[g * NC + t] = val;
    }
}

extern "C" void kernel_launch(void* const* d_in, const int* in_sizes, int n_in,
                              void* d_out, int out_size, void* d_ws, size_t ws_size,
                              hipStream_t stream) {
    const void* x     = d_in[0];
    const int*  ei    = (const int*)d_in[1];
    const int*  batch = (const int*)d_in[2];

    float* ws    = (float*)d_ws;
    bf16*  aggh  = (bf16*)(ws + OFF_AGGH);
    bf16*  xfh   = (bf16*)(ws + OFF_XF);
    bf16*  h1h   = (bf16*)(ws + OFF_H1);
    float* feats = ws + OFF_FEATS;
    float* csA   = ws + OFF_CSA;
    float* csB   = ws + OFF_CSB;
    float* sc6   = ws + OFF_SC6;
    float* sh6   = ws + OFF_SH6;
    int*   flags = (int*)(ws + OFF_FLAGS);
    bf16*  pb    = (bf16*)(ws + OFF_PARAMS);
    int*   deg   = (int*)(ws + OFF_DEG);
    int*   offs  = (int*)(ws + OFF_OFFS);
    int*   elist = (int*)(ws + OFF_ELIST);
    int*   bdeg  = (int*)(ws + OFF_BDEG);
    int*   boffs = (int*)(ws + OFF_BOFFS);
    int*   rank  = (int*)(ws + OFF_RANK);
    int*   part  = (int*)(ws + OFF_PART);
    int*   barst = (int*)(ws + OFF_BAR);

    bf16 *pW1T = pb + P_W1T, *pW2T = pb + P_W2T, *pWc1 = pb + P_WC1;
    bf16 *pb1 = pb + P_B1, *pg1 = pb + P_G1, *pbe1 = pb + P_BE1;
    bf16 *pb2 = pb + P_B2, *pg2 = pb + P_G2, *pbe2 = pb + P_BE2;
    bf16 *pbng = pb + P_BNG, *pbnb = pb + P_BNB;
    bf16 *pbc1 = pb + P_BC1, *pWc2 = pb + P_WC2, *pbc2 = pb + P_BC2;

    k_detect<<<1, 256, 0, stream>>>((const unsigned*)x, ei, batch, flags, bdeg);
    k_bhist<<<(NN + 255) / 256, 256, 0, stream>>>(flags, batch, bdeg, deg);
    k_bscan<<<1, 512, 0, stream>>>(bdeg, boffs, barst);
    k_bplace<<<(NN + 255) / 256, 256, 0, stream>>>(flags, batch, bdeg, rank);

    // fused x-convert + edge hist
    k_convert_hist<<<6250, 256, 0, stream>>>(flags, x, rank, xfh, ei, deg);

    SmallSrc ss;
    ss.s[0] = d_in[4];  ss.s[1] = d_in[5];  ss.s[2] = d_in[6];
    ss.s[3] = d_in[8];  ss.s[4] = d_in[9];  ss.s[5] = d_in[10];
    ss.s[6] = d_in[11]; ss.s[7] = d_in[12];
    ss.s[8] = d_in[14]; ss.s[9] = d_in[15]; ss.s[10] = d_in[16];
    k_convert_params<<<(245760 + 6538 + 255) / 256, 256, 0, stream>>>(
        flags, d_in[3], d_in[7], d_in[13], ss, pb);

    k_scan_part<<<49, 256, 0, stream>>>(deg, part);
    k_scan_apply<<<49, 256, 0, stream>>>(deg, part, offs);
    k_place<<<NE / 256, 256, 0, stream>>>(flags, ei, rank, deg, elist);

    for (int i = 0; i < NB; i++) {
        k_gather_pool<<<GATHER_BLOCKS + NG, 256, 0, stream>>>(
            offs, elist, xfh, aggh,
            (i == 0) ? nullptr : csB,
            pg2 + (i - 1) * DD, pbe2 + (i - 1) * DD, csA,
            boffs, (i == 0) ? nullptr : feats + (i - 1) * DD);
        k_gemm_pair<<<GP_BLOCKS, 512, 0, stream>>>(
            aggh, h1h, xfh,
            pW1T + i * DD * DD, pb1 + i * DD,
            pW2T + i * DD * DD, pb2 + i * DD,
            pg1 + i * DD, pbe1 + i * DD,
            csA, csB, barst);
    }

    k_tail<<<GP_BLOCKS, 256, 0, stream>>>(flags, xfh, boffs, csB,
                                          pg2 + (NB - 1) * DD, pbe2 + (NB - 1) * DD,
                                          feats, pbng, pbnb, sc6, sh6,
                                          pWc1, pbc1, pWc2, pbc2, d_out, barst);
}

// Round 16
// 687.154 us; speedup vs baseline: 1.4699x; 1.4699x over previous
//
#include <hip/hip_runtime.h>
#include <hip/hip_bf16.h>

#define NN 50000      // nodes
#define NE 800000     // edges
#define DD 128        // hidden dim
#define NB 5          // GIN blocks
#define NG 512        // graphs
#define NC 10         // classes
#define BN_EPS 1e-5f
#define EPS1 129.0f   // 1 + eps_gin
#define GATHER_BLOCKS 12500   // NN/4

typedef __hip_bfloat16 bf16;
typedef __attribute__((ext_vector_type(8))) short short8;
typedef __attribute__((ext_vector_type(4))) float f32x4;

__device__ __forceinline__ float b2f(const bf16 v) { return __bfloat162float(v); }
__device__ __forceinline__ float us2f(unsigned int s) {
    return __uint_as_float((s & 0xffffu) << 16);
}
__device__ __forceinline__ unsigned pack2(float a, float b) {
    union { bf16 h; unsigned short u; } ua, ub;
    ua.h = __float2bfloat16(a); ub.h = __float2bfloat16(b);
    return ((unsigned)ub.u << 16) | (unsigned)ua.u;
}
__device__ __forceinline__ short f2bfs(float f) {
    union { bf16 h; short s; } u; u.h = __float2bfloat16(f); return u.s;
}

// ---- workspace layout (float offsets) ----
// all node-indexed buffers live in the PERMUTED (graph-sorted) domain
#define OFF_AGGH   0            // bf16 [NN,128]
#define OFF_XF     3200000      // bf16 [NN,128]
#define OFF_H1     6400000      // bf16 [NN,128]  (GEMM1 out — no aliasing)
#define OFF_FEATS  9600000      // fp32 512*640
#define OFF_CSA    9927680      // 256: sum[0:128), sumsq[128:256)
#define OFF_CSB    9927936      // 256
#define OFF_SC6    9928192      // 640
#define OFF_SH6    9928832      // 640
#define OFF_FLAGS  9929472      // 8 ints
#define OFF_PARAMS 9929480      // bf16 region
#define OFF_DEG    10055680     // int 50000 (placement cursor after scan)
#define OFF_OFFS   10105680     // int 50001
#define OFF_ELIST  10155712     // int 800000
#define OFF_BDEG   10955712     // int 512
#define OFF_BOFFS  10956224     // int 513
#define OFF_RANK   10956800     // int 50000
#define OFF_PART   11006800     // int 64

// bf16 param region (bf16 element offsets)
#define P_W1T  0
#define P_W2T  81920
#define P_WC1  163840
#define P_B1   245760
#define P_G1   246400
#define P_BE1  247040
#define P_B2   247680
#define P_G2   248320
#define P_BE2  248960
#define P_BNG  249600
#define P_BNB  250240
#define P_BC1  250880
#define P_WC2  251008
#define P_BC2  252288

struct SmallSrc { const void* s[11]; };

// ---- dtype detection (also zeroes bdeg: runs before k_bhist) ----
__global__ void k_detect(const unsigned* __restrict__ xw, const int* __restrict__ eiw,
                         const int* __restrict__ bw, int* flags, int* __restrict__ bdeg) {
    __shared__ int sh[3];
    const int t = threadIdx.x;  // 256
    bdeg[t] = 0; bdeg[256 + t] = 0;
    if (t < 3) sh[t] = 0;
    __syncthreads();
    int c = 0;
    for (int i = 0; i < 16; i++) {
        unsigned w = xw[t * 16 + i];
        unsigned e = (w >> 7) & 0xff;
        c += (e >= 110 && e <= 131) ? 1 : 0;
    }
    atomicAdd(&sh[0], c);
    atomicAdd(&sh[1], (eiw[2 * t + 1] != 0) ? 1 : 0);
    atomicAdd(&sh[2], (bw[2 * t + 1] != 0) ? 1 : 0);
    __syncthreads();
    if (t == 0) {
        flags[0] = (sh[0] > 2048) ? 1 : 0;
        flags[1] = (sh[1] < 8) ? 1 : 0;
        flags[2] = (sh[2] < 8) ? 1 : 0;
    }
}

// ---- batch CSR; also zeroes deg (runs before k_hist) ----
__global__ void k_bhist(const int* __restrict__ flags, const int* __restrict__ batch,
                        int* __restrict__ bdeg, int* __restrict__ deg) {
    int n = blockIdx.x * 256 + threadIdx.x;
    if (n >= NN) return;
    deg[n] = 0;
    int g = flags[2] ? batch[2 * n] : batch[n];
    atomicAdd(&bdeg[g], 1);
}

__launch_bounds__(512)
__global__ void k_bscan(int* __restrict__ bdeg, int* __restrict__ boffs) {
    __shared__ int part[512];
    const int t = threadIdx.x;
    int d0 = bdeg[t];
    part[t] = d0;
    __syncthreads();
    for (int d = 1; d < 512; d <<= 1) {
        int v = (t >= d) ? part[t - d] : 0;
        __syncthreads();
        part[t] += v;
        __syncthreads();
    }
    int ex = part[t] - d0;
    boffs[t] = ex;
    bdeg[t] = ex;   // cursor
    if (t == 511) boffs[512] = part[511];
}

// rank[n] = permuted (graph-contiguous) id of old node n
__global__ void k_bplace(const int* __restrict__ flags, const int* __restrict__ batch,
                         int* __restrict__ bcur, int* __restrict__ rank) {
    int n = blockIdx.x * 256 + threadIdx.x;
    if (n >= NN) return;
    int g = flags[2] ? batch[2 * n] : batch[n];
    rank[n] = atomicAdd(&bcur[g], 1);
}

// x -> bf16 xfh in PERMUTED row order
__global__ void k_convert_x(const int* __restrict__ flags, const void* __restrict__ xr,
                            const int* __restrict__ rank, bf16* __restrict__ xfh) {
    int i = blockIdx.x * 256 + threadIdx.x;   // NN*DD/8 = 800000 chunks
    int r = i >> 4, seg = i & 15;
    uint4 o;
    if (flags[0]) {
        o = ((const uint4*)xr)[i];
    } else {
        float4 a = ((const float4*)xr)[2 * i], b = ((const float4*)xr)[2 * i + 1];
        o.x = pack2(a.x, a.y); o.y = pack2(a.z, a.w);
        o.z = pack2(b.x, b.y); o.w = pack2(b.z, b.w);
    }
    ((uint4*)xfh)[(long)rank[r] * 16 + seg] = o;
}

// unified param convert
__global__ void k_convert_params(const int* __restrict__ flags, const void* w1,
                                 const void* w2, const void* wc1, SmallSrc srcs,
                                 bf16* __restrict__ pb) {
    int i = blockIdx.x * 256 + threadIdx.x;
    if (i < 245760) {
        int which = i / 81920, j = i % 81920;
        const void* src = (which == 0) ? w1 : (which == 1) ? w2 : wc1;
        float v = flags[0] ? us2f(((const unsigned short*)src)[j]) : ((const float*)src)[j];
        if (which == 2) {
            pb[P_WC1 + j] = __float2bfloat16(v);
        } else {
            int layer = j >> 14, rem = j & 16383;
            int k = rem >> 7, c = rem & 127;
            bf16* dst = pb + (which == 0 ? P_W1T : P_W2T);
            dst[(layer << 14) + c * DD + k] = __float2bfloat16(v);
        }
    } else {
        int j = i - 245760;
        if (j >= 6538) return;
        int seg, off;
        if (j < 5120)      { seg = j / 640; off = j - seg * 640; }
        else if (j < 5248) { seg = 8;  off = j - 5120; }
        else if (j < 6528) { seg = 9;  off = j - 5248; }
        else               { seg = 10; off = j - 6528; }
        const void* s = srcs.s[seg];
        float v = flags[0] ? us2f(((const unsigned short*)s)[off]) : ((const float*)s)[off];
        pb[P_B1 + j] = __float2bfloat16(v);
    }
}

// ---- edge CSR (permuted domain) ----
__global__ void k_hist(const int* __restrict__ flags, const int* __restrict__ ei,
                       const int* __restrict__ rank, int* __restrict__ deg) {
    int e = blockIdx.x * 256 + threadIdx.x;   // NE
    int d = flags[1] ? ei[2 * NE + 2 * e] : ei[NE + e];
    atomicAdd(&deg[rank[d]], 1);
}

__global__ void k_scan_part(const int* __restrict__ deg, int* __restrict__ part) {
    __shared__ int red[256];
    const int b = blockIdx.x, t = threadIdx.x;   // 49 x 256
    int i0 = b * 1024 + t * 4;
    int s = 0;
    if (i0 + 3 < NN) {
        int4 v = *(const int4*)(deg + i0);
        s = v.x + v.y + v.z + v.w;
    } else {
        for (int k = 0; k < 4; k++) if (i0 + k < NN) s += deg[i0 + k];
    }
    red[t] = s;
    __syncthreads();
    for (int d = 128; d > 0; d >>= 1) {
        if (t < d) red[t] += red[t + d];
        __syncthreads();
    }
    if (t == 0) part[b] = red[0];
}

// scan_apply with inlined mid-scan: each block wave-scans the 49 partials.
__global__ void k_scan_apply(int* __restrict__ deg, const int* __restrict__ part,
                             int* __restrict__ offs) {
    __shared__ int red[256];
    __shared__ int base_sh, total_sh;
    const int b = blockIdx.x, t = threadIdx.x;   // 49 x 256
    if (t < 64) {
        int v = (t < 49) ? part[t] : 0;
        int s = v;
        for (int d = 1; d < 64; d <<= 1) {
            int x = __shfl_up(s, d);
            if (t >= d) s += x;
        }
        if (t == b)  base_sh = s - v;     // exclusive base for this block
        if (t == 48) total_sh = s;        // grand total
    }
    int i0 = b * 1024 + t * 4;
    int v[4]; int s = 0;
    #pragma unroll
    for (int k = 0; k < 4; k++) {
        int idx = i0 + k;
        v[k] = (idx < NN) ? deg[idx] : 0;
        s += v[k];
    }
    red[t] = s;
    __syncthreads();
    for (int d = 1; d < 256; d <<= 1) {
        int x = (t >= d) ? red[t - d] : 0;
        __syncthreads();
        red[t] += x;
        __syncthreads();
    }
    if (b == 0 && t == 0) offs[NN] = total_sh;
    int pre = base_sh + ((t == 0) ? 0 : red[t - 1]);
    #pragma unroll
    for (int k = 0; k < 4; k++) {
        int idx = i0 + k;
        if (idx < NN) { offs[idx] = pre; deg[idx] = pre; pre += v[k]; }
    }
}

__global__ void k_place(const int* __restrict__ flags, const int* __restrict__ ei,
                        const int* __restrict__ rank, int* __restrict__ curs,
                        int* __restrict__ elist) {
    int e = blockIdx.x * 256 + threadIdx.x;   // NE
    int s, d;
    if (flags[1]) { s = ei[2 * e]; d = ei[2 * NE + 2 * e]; }
    else          { s = ei[e];     d = ei[NE + e]; }
    elist[atomicAdd(&curs[rank[d]], 1)] = rank[s];
}

// pool body: per-graph sum of bn(xfh rows) -> feats[g][blk*128..]
__device__ __forceinline__ void pool_body(int g, int t, const bf16* __restrict__ xfh,
                                          const int* __restrict__ boffs,
                                          const float* __restrict__ csB,
                                          const bf16* __restrict__ g2,
                                          const bf16* __restrict__ be2,
                                          float* __restrict__ feats_blk) {
    __shared__ float2 red[3][64];
    const int l = t & 63;    // col pair index
    const int h = t >> 6;    // 0..3 row split
    const int lo = boffs[g], hi = boffs[g + 1];
    const unsigned* xw = (const unsigned*)xfh;
    float s0 = 0.f, s1 = 0.f;
    for (int n = lo + h; n < hi; n += 4) {
        unsigned p = xw[(long)n * 64 + l];
        s0 += us2f(p); s1 += us2f(p >> 16);
    }
    if (h) red[h - 1][l] = make_float2(s0, s1);
    __syncthreads();
    if (h == 0) {
        s0 += red[0][l].x + red[1][l].x + red[2][l].x;
        s1 += red[0][l].y + red[1][l].y + red[2][l].y;
        int c = l * 2;
        float mu0 = csB[c] * (1.f / NN);
        float var0 = csB[128 + c] * (1.f / NN) - mu0 * mu0;
        float sc0 = b2f(g2[c]) * rsqrtf(var0 + BN_EPS);
        float sh0 = b2f(be2[c]) - mu0 * sc0;
        float mu1 = csB[c + 1] * (1.f / NN);
        float var1 = csB[128 + c + 1] * (1.f / NN) - mu1 * mu1;
        float sc1 = b2f(g2[c + 1]) * rsqrtf(var1 + BN_EPS);
        float sh1 = b2f(be2[c + 1]) - mu1 * sc1;
        float cnt = (float)(hi - lo);
        float* fp = feats_blk + (long)g * (NB * DD) + c;
        fp[0] = sc0 * s0 + cnt * sh0;
        fp[1] = sc1 * s1 + cnt * sh1;
    }
}

// combined: blocks [0,12500) gather layer i; blocks [12500,13012) pool layer i-1.
__global__ void k_gather_pool(const int* __restrict__ offs, const int* __restrict__ elist,
                              const bf16* __restrict__ xfh, bf16* __restrict__ aggh,
                              const float* __restrict__ csB, const bf16* __restrict__ g2,
                              const bf16* __restrict__ be2, float* __restrict__ csA_zero,
                              const int* __restrict__ boffs, float* __restrict__ feats_prev) {
    if (blockIdx.x >= GATHER_BLOCKS) {
        if (feats_prev)
            pool_body(blockIdx.x - GATHER_BLOCKS, threadIdx.x, xfh, boffs,
                      csB, g2, be2, feats_prev);
        return;
    }
    if (blockIdx.x == 0) csA_zero[threadIdx.x] = 0.f;   // 256 floats
    const int w = threadIdx.x >> 6;
    const int lane = threadIdx.x & 63;
    const int n = blockIdx.x * 4 + w;
    const int base = offs[n], end = offs[n + 1];
    const unsigned* xw = (const unsigned*)xfh;
    unsigned sp = xw[(long)n * 64 + lane];
    float ax = EPS1 * us2f(sp), ay = EPS1 * us2f(sp >> 16);
    for (int i = base; i < end; i += 64) {
        int cnt = min(64, end - i);
        int e = (i + lane < end) ? elist[i + lane] : 0;
        int j = 0;
        for (; j + 16 <= cnt; j += 16) {
            unsigned p[16];
            #pragma unroll
            for (int q = 0; q < 16; q++) {
                int sj = __shfl(e, j + q);
                p[q] = xw[(long)sj * 64 + lane];
            }
            #pragma unroll
            for (int q = 0; q < 16; q++) {
                ax += us2f(p[q]); ay += us2f(p[q] >> 16);
            }
        }
        for (; j + 8 <= cnt; j += 8) {
            unsigned p[8];
            #pragma unroll
            for (int q = 0; q < 8; q++) {
                int sj = __shfl(e, j + q);
                p[q] = xw[(long)sj * 64 + lane];
            }
            #pragma unroll
            for (int q = 0; q < 8; q++) {
                ax += us2f(p[q]); ay += us2f(p[q] >> 16);
            }
        }
        for (; j < cnt; j++) {
            int sj = __shfl(e, j);
            unsigned p = xw[(long)sj * 64 + lane];
            ax += us2f(p); ay += us2f(p >> 16);
        }
    }
    if (csB) {
        int c = lane * 2;
        float fac = (float)(end - base) + EPS1;
        float mu0 = csB[c] * (1.f / NN);
        float var0 = csB[128 + c] * (1.f / NN) - mu0 * mu0;
        float sc0 = b2f(g2[c]) * rsqrtf(var0 + BN_EPS);
        float sh0 = b2f(be2[c]) - mu0 * sc0;
        float mu1 = csB[c + 1] * (1.f / NN);
        float var1 = csB[128 + c + 1] * (1.f / NN) - mu1 * mu1;
        float sc1 = b2f(g2[c + 1]) * rsqrtf(var1 + BN_EPS);
        float sh1 = b2f(be2[c + 1]) - mu1 * sc1;
        ax = sc0 * ax + fac * sh0;
        ay = sc1 * ay + fac * sh1;
    }
    ((unsigned*)aggh)[(long)n * 64 + lane] = pack2(ax, ay);
}

// standalone pool for the last layer
__launch_bounds__(256)
__global__ void k_pool(const bf16* __restrict__ xfh, const int* __restrict__ boffs,
                       const float* __restrict__ csB, const bf16* __restrict__ g2,
                       const bf16* __restrict__ be2, float* __restrict__ feats_blk) {
    pool_body(blockIdx.x, threadIdx.x, xfh, boffs, csB, g2, be2, feats_blk);
}

// ---- MFMA GEMM: 512 threads, 128 rows/block (391 blocks) ----
// A-direct fragments from global; W in LDS; epilogue v2: C staged through
// LDS (reusing Ws) for coalesced uint4 stores; stats shuffle-pre-reduced.
#define WS_S 136
__launch_bounds__(512)
__global__ void k_gemm_mfma(const bf16* __restrict__ A, const bf16* __restrict__ WT,
                            const bf16* __restrict__ bias,
                            const float* __restrict__ bn_cs, const bf16* __restrict__ bn_g,
                            const bf16* __restrict__ bn_be,
                            bf16* __restrict__ Out, float* __restrict__ cs_out,
                            float* cs_zero) {
    __shared__ short Ws[128 * WS_S];   // 34816 B (reused as C-staging)
    __shared__ float s_cs[256];
    __shared__ float s_sc[DD], s_sh[DD];
    const int t = threadIdx.x;
    const int row0 = blockIdx.x * 128;

    if (t < 256) {
        if (cs_zero && blockIdx.x == 0) cs_zero[t] = 0.f;
        s_cs[t] = 0.f;
    }
    if (bn_cs && t < DD) {
        float mu = bn_cs[t] * (1.f / NN);
        float var = bn_cs[128 + t] * (1.f / NN) - mu * mu;
        float sc = b2f(bn_g[t]) * rsqrtf(var + BN_EPS);
        s_sc[t] = sc;
        s_sh[t] = b2f(bn_be[t]) - mu * sc;
    }
    {   // stage WT (2048 uint4, 4 iters x 512 thr)
        const uint4* Wg = (const uint4*)WT;
        #pragma unroll
        for (int i = 0; i < 4; i++) {
            int idx = i * 512 + t;
            int row = idx >> 4, seg = idx & 15;
            *(uint4*)(&Ws[row * WS_S + seg * 8]) = Wg[idx];
        }
    }
    __syncthreads();

    const int w = t >> 6;          // wave 0..7 -> rows w*16..+15
    const int lane = t & 63;
    const int m = lane & 15;
    const int half = lane >> 4;
    const int r = row0 + w * 16 + m;

    short8 afrag[4];
    if (r < NN) {
        #pragma unroll
        for (int kk = 0; kk < 4; kk++)
            afrag[kk] = *(const short8*)(A + (long)r * DD + kk * 32 + half * 8);
        if (bn_cs) {
            #pragma unroll
            for (int kk = 0; kk < 4; kk++) {
                int c0 = kk * 32 + half * 8;
                uint4 p = *(uint4*)&afrag[kk];
                float v0 = us2f(p.x) * s_sc[c0+0] + s_sh[c0+0];
                float v1 = us2f(p.x >> 16) * s_sc[c0+1] + s_sh[c0+1];
                float v2 = us2f(p.y) * s_sc[c0+2] + s_sh[c0+2];
                float v3 = us2f(p.y >> 16) * s_sc[c0+3] + s_sh[c0+3];
                float v4 = us2f(p.z) * s_sc[c0+4] + s_sh[c0+4];
                float v5 = us2f(p.z >> 16) * s_sc[c0+5] + s_sh[c0+5];
                float v6 = us2f(p.w) * s_sc[c0+6] + s_sh[c0+6];
                float v7 = us2f(p.w >> 16) * s_sc[c0+7] + s_sh[c0+7];
                p.x = pack2(v0, v1); p.y = pack2(v2, v3);
                p.z = pack2(v4, v5); p.w = pack2(v6, v7);
                afrag[kk] = *(short8*)&p;
            }
        }
    } else {
        #pragma unroll
        for (int kk = 0; kk < 4; kk++) afrag[kk] = (short8){0,0,0,0,0,0,0,0};
    }

    f32x4 acc[8];
    #pragma unroll
    for (int nt = 0; nt < 8; nt++) acc[nt] = (f32x4){0.f, 0.f, 0.f, 0.f};

    #pragma unroll
    for (int nt = 0; nt < 8; nt++) {
        const short* wrow = &Ws[(nt * 16 + m) * WS_S + half * 8];
        #pragma unroll
        for (int kk = 0; kk < 4; kk++) {
            short8 b = *(const short8*)(wrow + kk * 32);
            acc[nt] = __builtin_amdgcn_mfma_f32_16x16x32_bf16(afrag[kk], b, acc[nt], 0, 0, 0);
        }
    }

    __syncthreads();               // all waves done reading Ws -> reuse as Cs
    short* Cs = Ws;
    #pragma unroll
    for (int nt = 0; nt < 8; nt++) {
        int col = nt * 16 + m;
        float bi = b2f(bias[col]);
        float ps = 0.f, pq = 0.f;
        #pragma unroll
        for (int reg = 0; reg < 4; reg++) {
            int rr = row0 + w * 16 + half * 4 + reg;
            float o = fmaxf(acc[nt][reg] + bi, 0.f);
            Cs[(w * 16 + half * 4 + reg) * WS_S + col] = f2bfs(o);
            if (rr < NN) { ps += o; pq += o * o; }
        }
        ps += __shfl_xor(ps, 16); ps += __shfl_xor(ps, 32);
        pq += __shfl_xor(pq, 16); pq += __shfl_xor(pq, 32);
        if (half == 0) {
            atomicAdd(&s_cs[col], ps);
            atomicAdd(&s_cs[128 + col], pq);
        }
    }
    __syncthreads();
    // vectorized store of the 128x128 tile
    #pragma unroll
    for (int i = 0; i < 4; i++) {
        int idx = i * 512 + t;
        int row = idx >> 4, seg = idx & 15;
        int rr = row0 + row;
        if (rr < NN)
            *(uint4*)(Out + (long)rr * DD + seg * 8) = *(uint4*)(&Cs[row * WS_S + seg * 8]);
    }
    if (t < 256) atomicAdd(&cs_out[t], s_cs[t]);
}

__global__ void k_feat_stats(const float* __restrict__ feats, const bf16* __restrict__ bn_g,
                             const bf16* __restrict__ bn_b, float* __restrict__ sc6,
                             float* __restrict__ sh6) {
    int j = blockIdx.x * 256 + threadIdx.x;
    if (j >= NB * DD) return;
    float s = 0.f, sq = 0.f;
    for (int g = 0; g < NG; g++) {
        float v = feats[(long)g * (NB * DD) + j];
        s += v; sq += v * v;
    }
    float mu = s / NG;
    float var = sq / NG - mu * mu;
    float sc = b2f(bn_g[j]) * rsqrtf(var + BN_EPS);
    sc6[j] = sc;
    sh6[j] = b2f(bn_b[j]) - mu * sc;
}

__launch_bounds__(128)
__global__ void k_head(const int* __restrict__ flags, const float* __restrict__ feats,
                       const float* __restrict__ sc6, const float* __restrict__ sh6,
                       const bf16* __restrict__ Wc1, const bf16* __restrict__ bc1,
                       const bf16* __restrict__ Wc2, const bf16* __restrict__ bc2,
                       void* out) {
    __shared__ float fs[NB * DD];
    __shared__ float f1[DD];
    __shared__ float lg[NC + 2];
    const int g = blockIdx.x, t = threadIdx.x;
    for (int j = t; j < NB * DD; j += 128)
        fs[j] = feats[(long)g * (NB * DD) + j] * sc6[j] + sh6[j];
    __syncthreads();
    float acc = b2f(bc1[t]);
    for (int j = 0; j < NB * DD; j++) acc += fs[j] * b2f(Wc1[j * DD + t]);
    f1[t] = fmaxf(acc, 0.f);
    __syncthreads();
    if (t < NC) {
        float a = b2f(bc2[t]);
        for (int k = 0; k < DD; k++) a += f1[k] * b2f(Wc2[k * NC + t]);
        lg[t] = a;
    }
    __syncthreads();
    if (t == 0) {
        float m = -1e30f;
        for (int c = 0; c < NC; c++) m = fmaxf(m, lg[c]);
        float s = 0.f;
        for (int c = 0; c < NC; c++) s += expf(lg[c] - m);
        lg[NC] = m + logf(s);
    }
    __syncthreads();
    if (t < NC) {
        float val = lg[t] - lg[NC];
        if (flags[0]) ((bf16*)out)[g * NC + t] = __float2bfloat16(val);
        else          ((float*)out)[g * NC + t] = val;
    }
}

extern "C" void kernel_launch(void* const* d_in, const int* in_sizes, int n_in,
                              void* d_out, int out_size, void* d_ws, size_t ws_size,
                              hipStream_t stream) {
    const void* x     = d_in[0];
    const int*  ei    = (const int*)d_in[1];
    const int*  batch = (const int*)d_in[2];

    float* ws    = (float*)d_ws;
    bf16*  aggh  = (bf16*)(ws + OFF_AGGH);
    bf16*  xfh   = (bf16*)(ws + OFF_XF);
    bf16*  h1h   = (bf16*)(ws + OFF_H1);
    float* feats = ws + OFF_FEATS;
    float* csA   = ws + OFF_CSA;
    float* csB   = ws + OFF_CSB;
    float* sc6   = ws + OFF_SC6;
    float* sh6   = ws + OFF_SH6;
    int*   flags = (int*)(ws + OFF_FLAGS);
    bf16*  pb    = (bf16*)(ws + OFF_PARAMS);
    int*   deg   = (int*)(ws + OFF_DEG);
    int*   offs  = (int*)(ws + OFF_OFFS);
    int*   elist = (int*)(ws + OFF_ELIST);
    int*   bdeg  = (int*)(ws + OFF_BDEG);
    int*   boffs = (int*)(ws + OFF_BOFFS);
    int*   rank  = (int*)(ws + OFF_RANK);
    int*   part  = (int*)(ws + OFF_PART);

    bf16 *pW1T = pb + P_W1T, *pW2T = pb + P_W2T, *pWc1 = pb + P_WC1;
    bf16 *pb1 = pb + P_B1, *pg1 = pb + P_G1, *pbe1 = pb + P_BE1;
    bf16 *pb2 = pb + P_B2, *pg2 = pb + P_G2, *pbe2 = pb + P_BE2;
    bf16 *pbng = pb + P_BNG, *pbnb = pb + P_BNB;
    bf16 *pbc1 = pb + P_BC1, *pWc2 = pb + P_WC2, *pbc2 = pb + P_BC2;

    k_detect<<<1, 256, 0, stream>>>((const unsigned*)x, ei, batch, flags, bdeg);

    // batch CSR -> node permutation (rank); k_bhist also zeroes deg
    k_bhist<<<(NN + 255) / 256, 256, 0, stream>>>(flags, batch, bdeg, deg);
    k_bscan<<<1, 512, 0, stream>>>(bdeg, boffs);
    k_bplace<<<(NN + 255) / 256, 256, 0, stream>>>(flags, batch, bdeg, rank);

    // x -> bf16, permuted rows
    k_convert_x<<<NN * DD / 8 / 256, 256, 0, stream>>>(flags, x, rank, xfh);

    // all params in one launch
    SmallSrc ss;
    ss.s[0] = d_in[4];  ss.s[1] = d_in[5];  ss.s[2] = d_in[6];
    ss.s[3] = d_in[8];  ss.s[4] = d_in[9];  ss.s[5] = d_in[10];
    ss.s[6] = d_in[11]; ss.s[7] = d_in[12];
    ss.s[8] = d_in[14]; ss.s[9] = d_in[15]; ss.s[10] = d_in[16];
    k_convert_params<<<(245760 + 6538 + 255) / 256, 256, 0, stream>>>(
        flags, d_in[3], d_in[7], d_in[13], ss, pb);

    // edge CSR in permuted domain
    k_hist<<<NE / 256, 256, 0, stream>>>(flags, ei, rank, deg);
    k_scan_part<<<49, 256, 0, stream>>>(deg, part);
    k_scan_apply<<<49, 256, 0, stream>>>(deg, part, offs);
    k_place<<<NE / 256, 256, 0, stream>>>(flags, ei, rank, deg, elist);

    const int gemm_blocks = (NN + 127) / 128;   // 391
    for (int i = 0; i < NB; i++) {
        // gather(i) + pool(i-1) in one launch
        k_gather_pool<<<GATHER_BLOCKS + NG, 256, 0, stream>>>(
            offs, elist, xfh, aggh,
            (i == 0) ? nullptr : csB,
            pg2 + (i - 1) * DD, pbe2 + (i - 1) * DD, csA,
            boffs, (i == 0) ? nullptr : feats + (i - 1) * DD);
        // GEMM1: aggh -> h1h, stats -> csA, zero csB
        k_gemm_mfma<<<gemm_blocks, 512, 0, stream>>>(aggh, pW1T + i * DD * DD, pb1 + i * DD,
                                                     nullptr, nullptr, nullptr,
                                                     h1h, csA, csB);
        // GEMM2: bn1(h1h) -> xfh, stats -> csB
        k_gemm_mfma<<<gemm_blocks, 512, 0, stream>>>(h1h, pW2T + i * DD * DD, pb2 + i * DD,
                                                     csA, pg1 + i * DD, pbe1 + i * DD,
                                                     xfh, csB, nullptr);
    }
    // final layer pool
    k_pool<<<NG, 256, 0, stream>>>(xfh, boffs, csB, pg2 + (NB - 1) * DD,
                                   pbe2 + (NB - 1) * DD, feats + (NB - 1) * DD);

    k_feat_stats<<<3, 256, 0, stream>>>(feats, pbng, pbnb, sc6, sh6);
    k_head<<<NG, 128, 0, stream>>>(flags, feats, sc6, sh6, pWc1, pbc1, pWc2, pbc2, d_out);
}

// Round 17
// 682.353 us; speedup vs baseline: 1.4802x; 1.0070x over previous
//
#include <hip/hip_runtime.h>
#include <hip/hip_bf16.h>

#define NN 50000      // nodes
#define NE 800000     // edges
#define DD 128        // hidden dim
#define NB 5          // GIN blocks
#define NG 512        // graphs
#define NC 10         // classes
#define BN_EPS 1e-5f
#define EPS1 129.0f   // 1 + eps_gin
#define GATHER_BLOCKS 12500   // NN/4

typedef __hip_bfloat16 bf16;
typedef __attribute__((ext_vector_type(8))) short short8;
typedef __attribute__((ext_vector_type(4))) float f32x4;

__device__ __forceinline__ float b2f(const bf16 v) { return __bfloat162float(v); }
__device__ __forceinline__ float us2f(unsigned int s) {
    return __uint_as_float((s & 0xffffu) << 16);
}
__device__ __forceinline__ unsigned pack2(float a, float b) {
    union { bf16 h; unsigned short u; } ua, ub;
    ua.h = __float2bfloat16(a); ub.h = __float2bfloat16(b);
    return ((unsigned)ub.u << 16) | (unsigned)ua.u;
}
__device__ __forceinline__ short f2bfs(float f) {
    union { bf16 h; short s; } u; u.h = __float2bfloat16(f); return u.s;
}

// ---- workspace layout (float offsets) ----
// all node-indexed buffers live in the PERMUTED (graph-sorted) domain
#define OFF_AGGH   0            // bf16 [NN,128]
#define OFF_XF     3200000      // bf16 [NN,128]
#define OFF_H1     6400000      // bf16 [NN,128]  (GEMM1 out — no aliasing)
#define OFF_FEATS  9600000      // fp32 512*640
#define OFF_CSA    9927680      // 256: sum[0:128), sumsq[128:256)
#define OFF_CSB    9927936      // 256
#define OFF_SC6    9928192      // 640
#define OFF_SH6    9928832      // 640
#define OFF_FLAGS  9929472      // 8 ints
#define OFF_PARAMS 9929480      // bf16 region
#define OFF_DEG    10055680     // int 50000 (placement cursor after scan)
#define OFF_OFFS   10105680     // int 50001
#define OFF_ELIST  10155712     // int 800000
#define OFF_BDEG   10955712     // int 512
#define OFF_BOFFS  10956224     // int 513
#define OFF_RANK   10956800     // int 50000
#define OFF_PART   11006800     // int 64

// bf16 param region (bf16 element offsets)
#define P_W1T  0
#define P_W2T  81920
#define P_WC1  163840
#define P_B1   245760
#define P_G1   246400
#define P_BE1  247040
#define P_B2   247680
#define P_G2   248320
#define P_BE2  248960
#define P_BNG  249600
#define P_BNB  250240
#define P_BC1  250880
#define P_WC2  251008
#define P_BC2  252288

struct SmallSrc { const void* s[11]; };

// ---- dtype detection (also zeroes bdeg: runs before k_bhist) ----
__global__ void k_detect(const unsigned* __restrict__ xw, const int* __restrict__ eiw,
                         const int* __restrict__ bw, int* flags, int* __restrict__ bdeg) {
    __shared__ int sh[3];
    const int t = threadIdx.x;  // 256
    bdeg[t] = 0; bdeg[256 + t] = 0;
    if (t < 3) sh[t] = 0;
    __syncthreads();
    int c = 0;
    for (int i = 0; i < 16; i++) {
        unsigned w = xw[t * 16 + i];
        unsigned e = (w >> 7) & 0xff;
        c += (e >= 110 && e <= 131) ? 1 : 0;
    }
    atomicAdd(&sh[0], c);
    atomicAdd(&sh[1], (eiw[2 * t + 1] != 0) ? 1 : 0);
    atomicAdd(&sh[2], (bw[2 * t + 1] != 0) ? 1 : 0);
    __syncthreads();
    if (t == 0) {
        flags[0] = (sh[0] > 2048) ? 1 : 0;
        flags[1] = (sh[1] < 8) ? 1 : 0;
        flags[2] = (sh[2] < 8) ? 1 : 0;
    }
}

// ---- batch CSR; also zeroes deg (runs before k_hist) ----
__global__ void k_bhist(const int* __restrict__ flags, const int* __restrict__ batch,
                        int* __restrict__ bdeg, int* __restrict__ deg) {
    int n = blockIdx.x * 256 + threadIdx.x;
    if (n >= NN) return;
    deg[n] = 0;
    int g = flags[2] ? batch[2 * n] : batch[n];
    atomicAdd(&bdeg[g], 1);
}

__launch_bounds__(512)
__global__ void k_bscan(int* __restrict__ bdeg, int* __restrict__ boffs) {
    __shared__ int part[512];
    const int t = threadIdx.x;
    int d0 = bdeg[t];
    part[t] = d0;
    __syncthreads();
    for (int d = 1; d < 512; d <<= 1) {
        int v = (t >= d) ? part[t - d] : 0;
        __syncthreads();
        part[t] += v;
        __syncthreads();
    }
    int ex = part[t] - d0;
    boffs[t] = ex;
    bdeg[t] = ex;   // cursor
    if (t == 511) boffs[512] = part[511];
}

// rank[n] = permuted (graph-contiguous) id of old node n
__global__ void k_bplace(const int* __restrict__ flags, const int* __restrict__ batch,
                         int* __restrict__ bcur, int* __restrict__ rank) {
    int n = blockIdx.x * 256 + threadIdx.x;
    if (n >= NN) return;
    int g = flags[2] ? batch[2 * n] : batch[n];
    rank[n] = atomicAdd(&bcur[g], 1);
}

// x -> bf16 xfh in PERMUTED row order
__global__ void k_convert_x(const int* __restrict__ flags, const void* __restrict__ xr,
                            const int* __restrict__ rank, bf16* __restrict__ xfh) {
    int i = blockIdx.x * 256 + threadIdx.x;   // NN*DD/8 = 800000 chunks
    int r = i >> 4, seg = i & 15;
    uint4 o;
    if (flags[0]) {
        o = ((const uint4*)xr)[i];
    } else {
        float4 a = ((const float4*)xr)[2 * i], b = ((const float4*)xr)[2 * i + 1];
        o.x = pack2(a.x, a.y); o.y = pack2(a.z, a.w);
        o.z = pack2(b.x, b.y); o.w = pack2(b.z, b.w);
    }
    ((uint4*)xfh)[(long)rank[r] * 16 + seg] = o;
}

// unified param convert
__global__ void k_convert_params(const int* __restrict__ flags, const void* w1,
                                 const void* w2, const void* wc1, SmallSrc srcs,
                                 bf16* __restrict__ pb) {
    int i = blockIdx.x * 256 + threadIdx.x;
    if (i < 245760) {
        int which = i / 81920, j = i % 81920;
        const void* src = (which == 0) ? w1 : (which == 1) ? w2 : wc1;
        float v = flags[0] ? us2f(((const unsigned short*)src)[j]) : ((const float*)src)[j];
        if (which == 2) {
            pb[P_WC1 + j] = __float2bfloat16(v);
        } else {
            int layer = j >> 14, rem = j & 16383;
            int k = rem >> 7, c = rem & 127;
            bf16* dst = pb + (which == 0 ? P_W1T : P_W2T);
            dst[(layer << 14) + c * DD + k] = __float2bfloat16(v);
        }
    } else {
        int j = i - 245760;
        if (j >= 6538) return;
        int seg, off;
        if (j < 5120)      { seg = j / 640; off = j - seg * 640; }
        else if (j < 5248) { seg = 8;  off = j - 5120; }
        else if (j < 6528) { seg = 9;  off = j - 5248; }
        else               { seg = 10; off = j - 6528; }
        const void* s = srcs.s[seg];
        float v = flags[0] ? us2f(((const unsigned short*)s)[off]) : ((const float*)s)[off];
        pb[P_B1 + j] = __float2bfloat16(v);
    }
}

// ---- edge CSR (permuted domain) ----
__global__ void k_hist(const int* __restrict__ flags, const int* __restrict__ ei,
                       const int* __restrict__ rank, int* __restrict__ deg) {
    int e = blockIdx.x * 256 + threadIdx.x;   // NE
    int d = flags[1] ? ei[2 * NE + 2 * e] : ei[NE + e];
    atomicAdd(&deg[rank[d]], 1);
}

__global__ void k_scan_part(const int* __restrict__ deg, int* __restrict__ part) {
    __shared__ int red[256];
    const int b = blockIdx.x, t = threadIdx.x;   // 49 x 256
    int i0 = b * 1024 + t * 4;
    int s = 0;
    if (i0 + 3 < NN) {
        int4 v = *(const int4*)(deg + i0);
        s = v.x + v.y + v.z + v.w;
    } else {
        for (int k = 0; k < 4; k++) if (i0 + k < NN) s += deg[i0 + k];
    }
    red[t] = s;
    __syncthreads();
    for (int d = 128; d > 0; d >>= 1) {
        if (t < d) red[t] += red[t + d];
        __syncthreads();
    }
    if (t == 0) part[b] = red[0];
}

// scan_apply with inlined mid-scan
__global__ void k_scan_apply(int* __restrict__ deg, const int* __restrict__ part,
                             int* __restrict__ offs) {
    __shared__ int red[256];
    __shared__ int base_sh, total_sh;
    const int b = blockIdx.x, t = threadIdx.x;   // 49 x 256
    if (t < 64) {
        int v = (t < 49) ? part[t] : 0;
        int s = v;
        for (int d = 1; d < 64; d <<= 1) {
            int x = __shfl_up(s, d);
            if (t >= d) s += x;
        }
        if (t == b)  base_sh = s - v;
        if (t == 48) total_sh = s;
    }
    int i0 = b * 1024 + t * 4;
    int v[4]; int s = 0;
    #pragma unroll
    for (int k = 0; k < 4; k++) {
        int idx = i0 + k;
        v[k] = (idx < NN) ? deg[idx] : 0;
        s += v[k];
    }
    red[t] = s;
    __syncthreads();
    for (int d = 1; d < 256; d <<= 1) {
        int x = (t >= d) ? red[t - d] : 0;
        __syncthreads();
        red[t] += x;
        __syncthreads();
    }
    if (b == 0 && t == 0) offs[NN] = total_sh;
    int pre = base_sh + ((t == 0) ? 0 : red[t - 1]);
    #pragma unroll
    for (int k = 0; k < 4; k++) {
        int idx = i0 + k;
        if (idx < NN) { offs[idx] = pre; deg[idx] = pre; pre += v[k]; }
    }
}

__global__ void k_place(const int* __restrict__ flags, const int* __restrict__ ei,
                        const int* __restrict__ rank, int* __restrict__ curs,
                        int* __restrict__ elist) {
    int e = blockIdx.x * 256 + threadIdx.x;   // NE
    int s, d;
    if (flags[1]) { s = ei[2 * e]; d = ei[2 * NE + 2 * e]; }
    else          { s = ei[e];     d = ei[NE + e]; }
    elist[atomicAdd(&curs[rank[d]], 1)] = rank[s];
}

// pool body: per-graph sum of bn(xfh rows) -> feats[g][blk*128..]
__device__ __forceinline__ void pool_body(int g, int t, const bf16* __restrict__ xfh,
                                          const int* __restrict__ boffs,
                                          const float* __restrict__ csB,
                                          const bf16* __restrict__ g2,
                                          const bf16* __restrict__ be2,
                                          float* __restrict__ feats_blk) {
    __shared__ float2 red[3][64];
    const int l = t & 63;    // col pair index
    const int h = t >> 6;    // 0..3 row split
    const int lo = boffs[g], hi = boffs[g + 1];
    const unsigned* xw = (const unsigned*)xfh;
    float s0 = 0.f, s1 = 0.f;
    for (int n = lo + h; n < hi; n += 4) {
        unsigned p = xw[(long)n * 64 + l];
        s0 += us2f(p); s1 += us2f(p >> 16);
    }
    if (h) red[h - 1][l] = make_float2(s0, s1);
    __syncthreads();
    if (h == 0) {
        s0 += red[0][l].x + red[1][l].x + red[2][l].x;
        s1 += red[0][l].y + red[1][l].y + red[2][l].y;
        int c = l * 2;
        float mu0 = csB[c] * (1.f / NN);
        float var0 = csB[128 + c] * (1.f / NN) - mu0 * mu0;
        float sc0 = b2f(g2[c]) * rsqrtf(var0 + BN_EPS);
        float sh0 = b2f(be2[c]) - mu0 * sc0;
        float mu1 = csB[c + 1] * (1.f / NN);
        float var1 = csB[128 + c + 1] * (1.f / NN) - mu1 * mu1;
        float sc1 = b2f(g2[c + 1]) * rsqrtf(var1 + BN_EPS);
        float sh1 = b2f(be2[c + 1]) - mu1 * sc1;
        float cnt = (float)(hi - lo);
        float* fp = feats_blk + (long)g * (NB * DD) + c;
        fp[0] = sc0 * s0 + cnt * sh0;
        fp[1] = sc1 * s1 + cnt * sh1;
    }
}

// combined: blocks [0,12500) gather layer i; blocks [12500,13012) pool layer i-1.
// Gather v2: uint2 lanes — 32 lanes cover a 256B row, so each wave-load
// fetches TWO edge rows (half = lane>>5 picks edge j+half). Self term
// counted in half 0 only; halves combined via shfl_xor(32) at the end.
__global__ void k_gather_pool(const int* __restrict__ offs, const int* __restrict__ elist,
                              const bf16* __restrict__ xfh, bf16* __restrict__ aggh,
                              const float* __restrict__ csB, const bf16* __restrict__ g2,
                              const bf16* __restrict__ be2, float* __restrict__ csA_zero,
                              const int* __restrict__ boffs, float* __restrict__ feats_prev) {
    if (blockIdx.x >= GATHER_BLOCKS) {
        if (feats_prev)
            pool_body(blockIdx.x - GATHER_BLOCKS, threadIdx.x, xfh, boffs,
                      csB, g2, be2, feats_prev);
        return;
    }
    if (blockIdx.x == 0) csA_zero[threadIdx.x] = 0.f;   // 256 floats
    const int w = threadIdx.x >> 6;
    const int lane = threadIdx.x & 63;
    const int half = lane >> 5;        // which of 2 concurrent edges
    const int ql = lane & 31;          // uint2 column chunk (4 bf16 cols)
    const int n = blockIdx.x * 4 + w;
    const int base = offs[n], end = offs[n + 1];
    const uint2* xw2 = (const uint2*)xfh;

    float a0, a1, a2, a3;
    {
        uint2 sp = xw2[(long)n * 32 + ql];
        float m = (half == 0) ? EPS1 : 0.f;
        a0 = m * us2f(sp.x); a1 = m * us2f(sp.x >> 16);
        a2 = m * us2f(sp.y); a3 = m * us2f(sp.y >> 16);
    }

    for (int i = base; i < end; i += 64) {
        int cnt = min(64, end - i);
        int e = (i + lane < end) ? elist[i + lane] : 0;
        int j = 0;
        for (; j + 16 <= cnt; j += 16) {       // 8 wave-loads = 16 edge rows
            uint2 p[8];
            #pragma unroll
            for (int q = 0; q < 8; q++) {
                int sj = __shfl(e, j + 2 * q + half);
                p[q] = xw2[(long)sj * 32 + ql];
            }
            #pragma unroll
            for (int q = 0; q < 8; q++) {
                a0 += us2f(p[q].x); a1 += us2f(p[q].x >> 16);
                a2 += us2f(p[q].y); a3 += us2f(p[q].y >> 16);
            }
        }
        for (; j + 2 <= cnt; j += 2) {
            int sj = __shfl(e, j + half);
            uint2 p = xw2[(long)sj * 32 + ql];
            a0 += us2f(p.x); a1 += us2f(p.x >> 16);
            a2 += us2f(p.y); a3 += us2f(p.y >> 16);
        }
        if (j < cnt && half == 0) {            // odd tail: half 0 only
            int sj = __shfl(e, j);
            uint2 p = xw2[(long)sj * 32 + ql];
            a0 += us2f(p.x); a1 += us2f(p.x >> 16);
            a2 += us2f(p.y); a3 += us2f(p.y >> 16);
        }
    }
    // combine the two halves (each lane pair ql, ql+32 holds same cols)
    a0 += __shfl_xor(a0, 32); a1 += __shfl_xor(a1, 32);
    a2 += __shfl_xor(a2, 32); a3 += __shfl_xor(a3, 32);

    if (csB) {
        int c = ql * 4;
        float fac = (float)(end - base) + EPS1;
        #pragma unroll
        for (int k = 0; k < 4; k++) {
            float mu = csB[c + k] * (1.f / NN);
            float var = csB[128 + c + k] * (1.f / NN) - mu * mu;
            float sc = b2f(g2[c + k]) * rsqrtf(var + BN_EPS);
            float sh = b2f(be2[c + k]) - mu * sc;
            float* ap = (k == 0) ? &a0 : (k == 1) ? &a1 : (k == 2) ? &a2 : &a3;
            *ap = sc * (*ap) + fac * sh;
        }
    }
    if (half == 0)
        ((uint2*)aggh)[(long)n * 32 + ql] = make_uint2(pack2(a0, a1), pack2(a2, a3));
}

// standalone pool for the last layer
__launch_bounds__(256)
__global__ void k_pool(const bf16* __restrict__ xfh, const int* __restrict__ boffs,
                       const float* __restrict__ csB, const bf16* __restrict__ g2,
                       const bf16* __restrict__ be2, float* __restrict__ feats_blk) {
    pool_body(blockIdx.x, threadIdx.x, xfh, boffs, csB, g2, be2, feats_blk);
}

// ---- MFMA GEMM: 512 threads, 128 rows/block (391 blocks) ----
#define WS_S 136
__launch_bounds__(512)
__global__ void k_gemm_mfma(const bf16* __restrict__ A, const bf16* __restrict__ WT,
                            const bf16* __restrict__ bias,
                            const float* __restrict__ bn_cs, const bf16* __restrict__ bn_g,
                            const bf16* __restrict__ bn_be,
                            bf16* __restrict__ Out, float* __restrict__ cs_out,
                            float* cs_zero) {
    __shared__ short Ws[128 * WS_S];   // 34816 B (reused as C-staging)
    __shared__ float s_cs[256];
    __shared__ float s_sc[DD], s_sh[DD];
    const int t = threadIdx.x;
    const int row0 = blockIdx.x * 128;

    if (t < 256) {
        if (cs_zero && blockIdx.x == 0) cs_zero[t] = 0.f;
        s_cs[t] = 0.f;
    }
    if (bn_cs && t < DD) {
        float mu = bn_cs[t] * (1.f / NN);
        float var = bn_cs[128 + t] * (1.f / NN) - mu * mu;
        float sc = b2f(bn_g[t]) * rsqrtf(var + BN_EPS);
        s_sc[t] = sc;
        s_sh[t] = b2f(bn_be[t]) - mu * sc;
    }
    {   // stage WT (2048 uint4, 4 iters x 512 thr)
        const uint4* Wg = (const uint4*)WT;
        #pragma unroll
        for (int i = 0; i < 4; i++) {
            int idx = i * 512 + t;
            int row = idx >> 4, seg = idx & 15;
            *(uint4*)(&Ws[row * WS_S + seg * 8]) = Wg[idx];
        }
    }
    __syncthreads();

    const int w = t >> 6;          // wave 0..7 -> rows w*16..+15
    const int lane = t & 63;
    const int m = lane & 15;
    const int half = lane >> 4;
    const int r = row0 + w * 16 + m;

    short8 afrag[4];
    if (r < NN) {
        #pragma unroll
        for (int kk = 0; kk < 4; kk++)
            afrag[kk] = *(const short8*)(A + (long)r * DD + kk * 32 + half * 8);
        if (bn_cs) {
            #pragma unroll
            for (int kk = 0; kk < 4; kk++) {
                int c0 = kk * 32 + half * 8;
                uint4 p = *(uint4*)&afrag[kk];
                float v0 = us2f(p.x) * s_sc[c0+0] + s_sh[c0+0];
                float v1 = us2f(p.x >> 16) * s_sc[c0+1] + s_sh[c0+1];
                float v2 = us2f(p.y) * s_sc[c0+2] + s_sh[c0+2];
                float v3 = us2f(p.y >> 16) * s_sc[c0+3] + s_sh[c0+3];
                float v4 = us2f(p.z) * s_sc[c0+4] + s_sh[c0+4];
                float v5 = us2f(p.z >> 16) * s_sc[c0+5] + s_sh[c0+5];
                float v6 = us2f(p.w) * s_sc[c0+6] + s_sh[c0+6];
                float v7 = us2f(p.w >> 16) * s_sc[c0+7] + s_sh[c0+7];
                p.x = pack2(v0, v1); p.y = pack2(v2, v3);
                p.z = pack2(v4, v5); p.w = pack2(v6, v7);
                afrag[kk] = *(short8*)&p;
            }
        }
    } else {
        #pragma unroll
        for (int kk = 0; kk < 4; kk++) afrag[kk] = (short8){0,0,0,0,0,0,0,0};
    }

    f32x4 acc[8];
    #pragma unroll
    for (int nt = 0; nt < 8; nt++) acc[nt] = (f32x4){0.f, 0.f, 0.f, 0.f};

    #pragma unroll
    for (int nt = 0; nt < 8; nt++) {
        const short* wrow = &Ws[(nt * 16 + m) * WS_S + half * 8];
        #pragma unroll
        for (int kk = 0; kk < 4; kk++) {
            short8 b = *(const short8*)(wrow + kk * 32);
            acc[nt] = __builtin_amdgcn_mfma_f32_16x16x32_bf16(afrag[kk], b, acc[nt], 0, 0, 0);
        }
    }

    __syncthreads();               // all waves done reading Ws -> reuse as Cs
    short* Cs = Ws;
    #pragma unroll
    for (int nt = 0; nt < 8; nt++) {
        int col = nt * 16 + m;
        float bi = b2f(bias[col]);
        float ps = 0.f, pq = 0.f;
        #pragma unroll
        for (int reg = 0; reg < 4; reg++) {
            int rr = row0 + w * 16 + half * 4 + reg;
            float o = fmaxf(acc[nt][reg] + bi, 0.f);
            Cs[(w * 16 + half * 4 + reg) * WS_S + col] = f2bfs(o);
            if (rr < NN) { ps += o; pq += o * o; }
        }
        ps += __shfl_xor(ps, 16); ps += __shfl_xor(ps, 32);
        pq += __shfl_xor(pq, 16); pq += __shfl_xor(pq, 32);
        if (half == 0) {
            atomicAdd(&s_cs[col], ps);
            atomicAdd(&s_cs[128 + col], pq);
        }
    }
    __syncthreads();
    // vectorized store of the 128x128 tile
    #pragma unroll
    for (int i = 0; i < 4; i++) {
        int idx = i * 512 + t;
        int row = idx >> 4, seg = idx & 15;
        int rr = row0 + row;
        if (rr < NN)
            *(uint4*)(Out + (long)rr * DD + seg * 8) = *(uint4*)(&Cs[row * WS_S + seg * 8]);
    }
    if (t < 256) atomicAdd(&cs_out[t], s_cs[t]);
}

__global__ void k_feat_stats(const float* __restrict__ feats, const bf16* __restrict__ bn_g,
                             const bf16* __restrict__ bn_b, float* __restrict__ sc6,
                             float* __restrict__ sh6) {
    int j = blockIdx.x * 256 + threadIdx.x;
    if (j >= NB * DD) return;
    float s = 0.f, sq = 0.f;
    for (int g = 0; g < NG; g++) {
        float v = feats[(long)g * (NB * DD) + j];
        s += v; sq += v * v;
    }
    float mu = s / NG;
    float var = sq / NG - mu * mu;
    float sc = b2f(bn_g[j]) * rsqrtf(var + BN_EPS);
    sc6[j] = sc;
    sh6[j] = b2f(bn_b[j]) - mu * sc;
}

__launch_bounds__(128)
__global__ void k_head(const int* __restrict__ flags, const float* __restrict__ feats,
                       const float* __restrict__ sc6, const float* __restrict__ sh6,
                       const bf16* __restrict__ Wc1, const bf16* __restrict__ bc1,
                       const bf16* __restrict__ Wc2, const bf16* __restrict__ bc2,
                       void* out) {
    __shared__ float fs[NB * DD];
    __shared__ float f1[DD];
    __shared__ float lg[NC + 2];
    const int g = blockIdx.x, t = threadIdx.x;
    for (int j = t; j < NB * DD; j += 128)
        fs[j] = feats[(long)g * (NB * DD) + j] * sc6[j] + sh6[j];
    __syncthreads();
    float acc = b2f(bc1[t]);
    for (int j = 0; j < NB * DD; j++) acc += fs[j] * b2f(Wc1[j * DD + t]);
    f1[t] = fmaxf(acc, 0.f);
    __syncthreads();
    if (t < NC) {
        float a = b2f(bc2[t]);
        for (int k = 0; k < DD; k++) a += f1[k] * b2f(Wc2[k * NC + t]);
        lg[t] = a;
    }
    __syncthreads();
    if (t == 0) {
        float m = -1e30f;
        for (int c = 0; c < NC; c++) m = fmaxf(m, lg[c]);
        float s = 0.f;
        for (int c = 0; c < NC; c++) s += expf(lg[c] - m);
        lg[NC] = m + logf(s);
    }
    __syncthreads();
    if (t < NC) {
        float val = lg[t] - lg[NC];
        if (flags[0]) ((bf16*)out)[g * NC + t] = __float2bfloat16(val);
        else          ((float*)out)[g * NC + t] = val;
    }
}

extern "C" void kernel_launch(void* const* d_in, const int* in_sizes, int n_in,
                              void* d_out, int out_size, void* d_ws, size_t ws_size,
                              hipStream_t stream) {
    const void* x     = d_in[0];
    const int*  ei    = (const int*)d_in[1];
    const int*  batch = (const int*)d_in[2];

    float* ws    = (float*)d_ws;
    bf16*  aggh  = (bf16*)(ws + OFF_AGGH);
    bf16*  xfh   = (bf16*)(ws + OFF_XF);
    bf16*  h1h   = (bf16*)(ws + OFF_H1);
    float* feats = ws + OFF_FEATS;
    float* csA   = ws + OFF_CSA;
    float* csB   = ws + OFF_CSB;
    float* sc6   = ws + OFF_SC6;
    float* sh6   = ws + OFF_SH6;
    int*   flags = (int*)(ws + OFF_FLAGS);
    bf16*  pb    = (bf16*)(ws + OFF_PARAMS);
    int*   deg   = (int*)(ws + OFF_DEG);
    int*   offs  = (int*)(ws + OFF_OFFS);
    int*   elist = (int*)(ws + OFF_ELIST);
    int*   bdeg  = (int*)(ws + OFF_BDEG);
    int*   boffs = (int*)(ws + OFF_BOFFS);
    int*   rank  = (int*)(ws + OFF_RANK);
    int*   part  = (int*)(ws + OFF_PART);

    bf16 *pW1T = pb + P_W1T, *pW2T = pb + P_W2T, *pWc1 = pb + P_WC1;
    bf16 *pb1 = pb + P_B1, *pg1 = pb + P_G1, *pbe1 = pb + P_BE1;
    bf16 *pb2 = pb + P_B2, *pg2 = pb + P_G2, *pbe2 = pb + P_BE2;
    bf16 *pbng = pb + P_BNG, *pbnb = pb + P_BNB;
    bf16 *pbc1 = pb + P_BC1, *pWc2 = pb + P_WC2, *pbc2 = pb + P_BC2;

    k_detect<<<1, 256, 0, stream>>>((const unsigned*)x, ei, batch, flags, bdeg);

    // batch CSR -> node permutation (rank); k_bhist also zeroes deg
    k_bhist<<<(NN + 255) / 256, 256, 0, stream>>>(flags, batch, bdeg, deg);
    k_bscan<<<1, 512, 0, stream>>>(bdeg, boffs);
    k_bplace<<<(NN + 255) / 256, 256, 0, stream>>>(flags, batch, bdeg, rank);

    // x -> bf16, permuted rows
    k_convert_x<<<NN * DD / 8 / 256, 256, 0, stream>>>(flags, x, rank, xfh);

    // all params in one launch
    SmallSrc ss;
    ss.s[0] = d_in[4];  ss.s[1] = d_in[5];  ss.s[2] = d_in[6];
    ss.s[3] = d_in[8];  ss.s[4] = d_in[9];  ss.s[5] = d_in[10];
    ss.s[6] = d_in[11]; ss.s[7] = d_in[12];
    ss.s[8] = d_in[14]; ss.s[9] = d_in[15]; ss.s[10] = d_in[16];
    k_convert_params<<<(245760 + 6538 + 255) / 256, 256, 0, stream>>>(
        flags, d_in[3], d_in[7], d_in[13], ss, pb);

    // edge CSR in permuted domain
    k_hist<<<NE / 256, 256, 0, stream>>>(flags, ei, rank, deg);
    k_scan_part<<<49, 256, 0, stream>>>(deg, part);
    k_scan_apply<<<49, 256, 0, stream>>>(deg, part, offs);
    k_place<<<NE / 256, 256, 0, stream>>>(flags, ei, rank, deg, elist);

    const int gemm_blocks = (NN + 127) / 128;   // 391
    for (int i = 0; i < NB; i++) {
        // gather(i) + pool(i-1) in one launch
        k_gather_pool<<<GATHER_BLOCKS + NG, 256, 0, stream>>>(
            offs, elist, xfh, aggh,
            (i == 0) ? nullptr : csB,
            pg2 + (i - 1) * DD, pbe2 + (i - 1) * DD, csA,
            boffs, (i == 0) ? nullptr : feats + (i - 1) * DD);
        // GEMM1: aggh -> h1h, stats -> csA, zero csB
        k_gemm_mfma<<<gemm_blocks, 512, 0, stream>>>(aggh, pW1T + i * DD * DD, pb1 + i * DD,
                                                     nullptr, nullptr, nullptr,
                                                     h1h, csA, csB);
        // GEMM2: bn1(h1h) -> xfh, stats -> csB
        k_gemm_mfma<<<gemm_blocks, 512, 0, stream>>>(h1h, pW2T + i * DD * DD, pb2 + i * DD,
                                                     csA, pg1 + i * DD, pbe1 + i * DD,
                                                     xfh, csB, nullptr);
    }
    // final layer pool
    k_pool<<<NG, 256, 0, stream>>>(xfh, boffs, csB, pg2 + (NB - 1) * DD,
                                   pbe2 + (NB - 1) * DD, feats + (NB - 1) * DD);

    k_feat_stats<<<3, 256, 0, stream>>>(feats, pbng, pbnb, sc6, sh6);
    k_head<<<NG, 128, 0, stream>>>(flags, feats, sc6, sh6, pWc1, pbc1, pWc2, pbc2, d_out);
}